// Round 1
// baseline (232.046 us; speedup 1.0000x reference)
//
#include <hip/hip_runtime.h>
#include <math.h>

// GatingNetwork: logits = x[T,D] @ W[D,E] + b; weights = softmax(logits);
// (topk_w[T,2], topk_idx[T,2], weights[T,E]) concatenated flat in d_out (fp32;
// indices stored as float values).
//
// T=16384 D=2048 E=64. fp32 GEMM (no fp32 MFMA on CDNA4 -> vector FMA).
// 256 blocks x 256 threads; per-block tile 64 tokens x 64 experts; BK=32;
// double-buffered LDS; 4x4 accumulator micro-tile per thread.

#define T_TOK 16384
#define DMOD 2048
#define NEXP 64
#define TM 64
#define BK 32
#define NT 256
#define NCHUNK (DMOD / BK)

__global__ __launch_bounds__(NT) void gating_kernel(
    const float* __restrict__ x, const float* __restrict__ W,
    const float* __restrict__ bias, float* __restrict__ out) {
  // xs transposed [BK][TM]: 4-token x fragment = one ds_read_b128 (broadcast-heavy, conflict-free)
  __shared__ float xs[2][BK][TM];      // 16 KB
  __shared__ float ws[2][BK][NEXP];    // 16 KB
  __shared__ float lg[TM][NEXP + 1];   // +1 pad -> (t+e)%32 banks, 2-way max (free)
  __shared__ float red_m[TM];
  __shared__ float red_s[TM];

  const int tid = threadIdx.x;
  const int t0 = blockIdx.x * TM;
  const int ty = tid >> 4;   // 0..15 -> tokens ty*4..+3
  const int tx = tid & 15;   // 0..15 -> experts tx*4..+3
  const int st_t = tid & 63; // staging: token within tile (wave covers 64 tokens)
  const int st_c = tid >> 6; // staging: which 4-float d-column group

  float acc[4][4];
#pragma unroll
  for (int i = 0; i < 4; ++i)
#pragma unroll
    for (int e = 0; e < 4; ++e) acc[i][e] = 0.f;

  const float* xg = x + (size_t)(t0 + st_t) * DMOD + st_c * 4;
  const float* wg = W + tid * 4;

  // ---- stage chunk 0 into buffer 0 ----
  {
    const float4 a  = *(const float4*)(xg);
    const float4 b  = *(const float4*)(xg + 16);
    const float4 wa = *(const float4*)(wg);
    const float4 wb = *(const float4*)(wg + 1024);
    const int d0 = st_c * 4;
    xs[0][d0 + 0][st_t] = a.x;  xs[0][d0 + 1][st_t] = a.y;
    xs[0][d0 + 2][st_t] = a.z;  xs[0][d0 + 3][st_t] = a.w;
    xs[0][16 + d0 + 0][st_t] = b.x;  xs[0][16 + d0 + 1][st_t] = b.y;
    xs[0][16 + d0 + 2][st_t] = b.z;  xs[0][16 + d0 + 3][st_t] = b.w;
    *(float4*)(&ws[0][0][0] + tid * 4) = wa;
    *(float4*)(&ws[0][0][0] + 1024 + tid * 4) = wb;
  }
  __syncthreads();

  int buf = 0;
  for (int k = 0; k < NCHUNK; ++k) {
    // prefetch chunk k+1 into registers (VMEM latency hidden under compute)
    float4 pa, pb, pwa, pwb;
    const bool has_next = (k + 1 < NCHUNK);
    if (has_next) {
      const int kd = (k + 1) * BK;
      pa  = *(const float4*)(xg + kd);
      pb  = *(const float4*)(xg + kd + 16);
      pwa = *(const float4*)(wg + (size_t)kd * NEXP);
      pwb = *(const float4*)(wg + (size_t)kd * NEXP + 1024);
    }
    // compute: 32 j-steps x (2 ds_read_b128 + 16 FMA)
#pragma unroll
    for (int j = 0; j < BK; ++j) {
      const float4 xv = *(const float4*)&xs[buf][j][ty * 4];
      const float4 wv = *(const float4*)&ws[buf][j][tx * 4];
      acc[0][0] = fmaf(xv.x, wv.x, acc[0][0]);
      acc[0][1] = fmaf(xv.x, wv.y, acc[0][1]);
      acc[0][2] = fmaf(xv.x, wv.z, acc[0][2]);
      acc[0][3] = fmaf(xv.x, wv.w, acc[0][3]);
      acc[1][0] = fmaf(xv.y, wv.x, acc[1][0]);
      acc[1][1] = fmaf(xv.y, wv.y, acc[1][1]);
      acc[1][2] = fmaf(xv.y, wv.z, acc[1][2]);
      acc[1][3] = fmaf(xv.y, wv.w, acc[1][3]);
      acc[2][0] = fmaf(xv.z, wv.x, acc[2][0]);
      acc[2][1] = fmaf(xv.z, wv.y, acc[2][1]);
      acc[2][2] = fmaf(xv.z, wv.z, acc[2][2]);
      acc[2][3] = fmaf(xv.z, wv.w, acc[2][3]);
      acc[3][0] = fmaf(xv.w, wv.x, acc[3][0]);
      acc[3][1] = fmaf(xv.w, wv.y, acc[3][1]);
      acc[3][2] = fmaf(xv.w, wv.z, acc[3][2]);
      acc[3][3] = fmaf(xv.w, wv.w, acc[3][3]);
    }
    // store prefetched tile into the other buffer
    if (has_next) {
      const int nb = buf ^ 1;
      const int d0 = st_c * 4;
      xs[nb][d0 + 0][st_t] = pa.x;  xs[nb][d0 + 1][st_t] = pa.y;
      xs[nb][d0 + 2][st_t] = pa.z;  xs[nb][d0 + 3][st_t] = pa.w;
      xs[nb][16 + d0 + 0][st_t] = pb.x;  xs[nb][16 + d0 + 1][st_t] = pb.y;
      xs[nb][16 + d0 + 2][st_t] = pb.z;  xs[nb][16 + d0 + 3][st_t] = pb.w;
      *(float4*)(&ws[nb][0][0] + tid * 4) = pwa;
      *(float4*)(&ws[nb][0][0] + 1024 + tid * 4) = pwb;
    }
    __syncthreads();
    buf ^= 1;
  }

  // ---- epilogue: logits -> LDS (with bias) ----
#pragma unroll
  for (int i = 0; i < 4; ++i)
#pragma unroll
    for (int e = 0; e < 4; ++e)
      lg[ty * 4 + i][tx * 4 + e] = acc[i][e] + bias[tx * 4 + e];
  __syncthreads();

  // per-token softmax stats + top-2 (wave 0; one lane per token; bank-free via +1 pad)
  if (tid < TM) {
    float m = -INFINITY;
    for (int e = 0; e < NEXP; ++e) m = fmaxf(m, lg[tid][e]);
    float s = 0.f, b1 = -INFINITY, b2 = -INFINITY;
    int i1 = 0, i2 = 0;
    for (int e = 0; e < NEXP; ++e) {
      const float v = lg[tid][e];
      s += expf(v - m);
      if (v > b1) {           // strict > : ties keep lowest index (jax top_k order)
        b2 = b1; i2 = i1; b1 = v; i1 = e;
      } else if (v > b2) {
        b2 = v; i2 = e;
      }
    }
    const float inv = 1.f / s;
    const int t = t0 + tid;
    out[2 * t + 0] = expf(b1 - m) * inv;          // topk_weights
    out[2 * t + 1] = expf(b2 - m) * inv;
    out[2 * T_TOK + 2 * t + 0] = (float)i1;       // topk_indices (as float)
    out[2 * T_TOK + 2 * t + 1] = (float)i2;
    red_m[tid] = m;
    red_s[tid] = inv;
  }
  __syncthreads();

  // full softmax weights, coalesced: consecutive tid -> consecutive e
#pragma unroll
  for (int r = 0; r < (TM * NEXP) / NT; ++r) {
    const int idx = r * NT + tid;
    const int tt = idx >> 6;
    const int e = idx & 63;
    out[4 * T_TOK + (size_t)(t0 + tt) * NEXP + e] =
        expf(lg[tt][e] - red_m[tt]) * red_s[tt];
  }
}

extern "C" void kernel_launch(void* const* d_in, const int* in_sizes, int n_in,
                              void* d_out, int out_size, void* d_ws, size_t ws_size,
                              hipStream_t stream) {
  const float* x = (const float*)d_in[0];
  const float* W = (const float*)d_in[1];
  const float* b = (const float*)d_in[2];
  float* out = (float*)d_out;
  gating_kernel<<<dim3(T_TOK / TM), dim3(NT), 0, stream>>>(x, W, b, out);
}